// Round 11
// baseline (175.585 us; speedup 1.0000x reference)
//
#include <hip/hip_runtime.h>
#include <hip/hip_bf16.h>

#define S_LEN 4096
#define BATCH 8
#define DMODEL 1024
#define HDIM 256
#define NTYPES 8
#define KMAX 20
#define NSLOT (BATCH*KMAX)
#define THRESH 0.4f
#define LN_EPS 1e-5f
#define RSQRT2 0.70710678118654752f

// d_out offsets (f32 elements), reference return order
#define O_SCORES 0
#define O_ENH    32768
#define O_TLOG   196608
#define O_ESC    197888
#define O_TPROB  198048
#define O_TYPE   199328
#define O_VALIDK 199488

// ws layout (4-byte units)
#define WS_SCORES   0
#define WS_SPSTART  32768
#define WS_SPLEN    49152
#define WS_SPAVG    65536
#define WS_NSP      81920
#define WS_SELSTART 81936
#define WS_SELLEN   82096
#define WS_SELAVG   82256
#define WS_SELVALID 82416
// W1 hi/lo f16 image: 64 chunks x 8192 f16 (hi[4096] || lo[4096] per 16-k chunk)
#define WS_IMG      82576    // 262144 f32 = 1 MB

typedef _Float16 f16x8 __attribute__((ext_vector_type(8)));
typedef float f32x16 __attribute__((ext_vector_type(16)));

#define ARS 72   // A row stride in f16 (144 B = 9 16B-slots; odd slot stride ->
                 // reads AND writes spread uniformly over all 8 LDS windows)

__device__ __forceinline__ float gelu_exact(float v) {
    return 0.5f * v * (1.0f + erff(v * RSQRT2));
}

// ---------------- K0: W1 -> chunked hi/lo f16 image (BK=16) --------
// chunk c (0..63): hi at [c*8192 + col*16 + k], lo at +4096
__global__ __launch_bounds__(256) void k_prep(
    const float* __restrict__ W1, _Float16* __restrict__ IMG)
{
    const int c = blockIdx.x;     // 16-k chunk
    const int n = threadIdx.x;    // col
    f16x8 hv[2], lv[2];
#pragma unroll
    for (int j = 0; j < 2; j++)
#pragma unroll
        for (int e = 0; e < 8; e++) {
            float w = W1[(size_t)(c * 16 + j * 8 + e) * HDIM + n];
            _Float16 h = (_Float16)w;
            hv[j][e] = h;
            lv[j][e] = (_Float16)(w - (float)h);
        }
    const int off = c * 8192 + n * 16;
    *(f16x8*)&IMG[off] = hv[0];
    *(f16x8*)&IMG[off + 8] = hv[1];
    *(f16x8*)&IMG[off + 4096] = lv[0];
    *(f16x8*)&IMG[off + 4096 + 8] = lv[1];
}

// ---------------- K1: scorer MLP — BK=64 supersteps, B from global ----------
// 512 blocks x 512 thr (8 waves); tile 64x256; wave tile 64x32 (no B redundancy)
__global__ __launch_bounds__(512, 4) void k_score8(
    const float* __restrict__ X, const _Float16* __restrict__ IMG,
    const float* __restrict__ B1, const float* __restrict__ G,
    const float* __restrict__ BE, const float* __restrict__ W2,
    const float* __restrict__ B2, const int* __restrict__ MASK,
    float* __restrict__ scf, float* __restrict__ out)
{
    union SM {
        _Float16 A[2][64 * ARS];   // [hi/lo][row*ARS + k]  18 KB, single buffer
        struct { float part2[64 * 9]; float mul[64]; float rsl[64]; } e;
    };
    __shared__ SM sm;

    const int tid = threadIdx.x;
    const int lane = tid & 63, wid = tid >> 6;
    const int lr = lane & 31, lh = lane >> 5;
    const int wn = wid * 32;             // wave col offset: 8 waves cover 256 cols
    const int tok0 = blockIdx.x * 64;

    // X loader: thread covers 8 consecutive f32 of one row per superstep
    const int xrow = tid >> 3, xkg = tid & 7;
    const float* xbase = X + (size_t)(tok0 + xrow) * DMODEL + xkg * 8;
    const int awoff = xrow * ARS + xkg * 8;          // A write f16 idx
    // A read bases (per sub-chunk kk add kk*16)
    const int ar0 = lr * ARS + lh * 8;               // mi=0 rows 0..31
    const int ar1 = (32 + lr) * ARS + lh * 8;        // mi=1 rows 32..63
    // B fragment f16 offset within a chunk
    const int bo = (wn + lr) * 16 + lh * 8;

    f32x16 acc0 = (f32x16)0.0f, acc1 = (f32x16)0.0f;

    // preload X(0)
    float4 xa = *(const float4*)xbase;
    float4 xb = *(const float4*)(xbase + 4);

    for (int s = 0; s < 16; ++s) {
        // convert + write A (single buffer; barrier-2 of previous iter protects)
        {
            float xv[8] = {xa.x, xa.y, xa.z, xa.w, xb.x, xb.y, xb.z, xb.w};
            f16x8 ah, al;
#pragma unroll
            for (int e = 0; e < 8; e++) {
                _Float16 h = (_Float16)xv[e];
                ah[e] = h;
                al[e] = (_Float16)(xv[e] - (float)h);
            }
            *(f16x8*)&sm.A[0][awoff] = ah;
            *(f16x8*)&sm.A[1][awoff] = al;
        }
        __syncthreads();                 // A visible to all waves

        // issue next superstep's X loads; they drain at the closing barrier,
        // hidden under the 24-MFMA compute window below
        if (s < 15) {
            xa = *(const float4*)(xbase + (s + 1) * 64);
            xb = *(const float4*)(xbase + (s + 1) * 64 + 4);
        }

        // 4 sub-chunks, straight-line: compiler hoists B loads + counts waits
#pragma unroll
        for (int kk = 0; kk < 4; ++kk) {
            const _Float16* ib = IMG + (size_t)(s * 4 + kk) * 8192;
            f16x8 bh = *(const f16x8*)&ib[bo];
            f16x8 bl = *(const f16x8*)&ib[4096 + bo];
            f16x8 fa0h = *(const f16x8*)&sm.A[0][ar0 + kk * 16];
            f16x8 fa0l = *(const f16x8*)&sm.A[1][ar0 + kk * 16];
            f16x8 fa1h = *(const f16x8*)&sm.A[0][ar1 + kk * 16];
            f16x8 fa1l = *(const f16x8*)&sm.A[1][ar1 + kk * 16];
            acc0 = __builtin_amdgcn_mfma_f32_32x32x16_f16(fa0h, bh, acc0, 0, 0, 0);
            acc0 = __builtin_amdgcn_mfma_f32_32x32x16_f16(fa0l, bh, acc0, 0, 0, 0);
            acc0 = __builtin_amdgcn_mfma_f32_32x32x16_f16(fa0h, bl, acc0, 0, 0, 0);
            acc1 = __builtin_amdgcn_mfma_f32_32x32x16_f16(fa1h, bh, acc1, 0, 0, 0);
            acc1 = __builtin_amdgcn_mfma_f32_32x32x16_f16(fa1l, bh, acc1, 0, 0, 0);
            acc1 = __builtin_amdgcn_mfma_f32_32x32x16_f16(fa1h, bl, acc1, 0, 0, 0);
        }
        __syncthreads();                 // A reads done; next write may proceed
    }

    // ---- epilogue: bias, LN over 256 cols, GELU, dot w2, sigmoid, mask ----
    // C/D: col = wn + lr; acc0 -> row (r&3)+8*(r>>2)+4*lh; acc1 -> +32
    const float bc = B1[wn + lr];
    const float gc = G[wn + lr];
    const float bec = BE[wn + lr];
    const float wc = W2[wn + lr];
#pragma unroll
    for (int r = 0; r < 16; r++) { acc0[r] += bc; acc1[r] += bc; }

    // pass 1: mean
#pragma unroll
    for (int r = 0; r < 16; r++) {
        float p0 = acc0[r], p1 = acc1[r];
        p0 += __shfl_xor(p0, 1);  p0 += __shfl_xor(p0, 2);
        p0 += __shfl_xor(p0, 4);  p0 += __shfl_xor(p0, 8);
        p0 += __shfl_xor(p0, 16);
        p1 += __shfl_xor(p1, 1);  p1 += __shfl_xor(p1, 2);
        p1 += __shfl_xor(p1, 4);  p1 += __shfl_xor(p1, 8);
        p1 += __shfl_xor(p1, 16);
        int row = (r & 3) + 8 * (r >> 2) + 4 * lh;
        if (lr == 0) {
            sm.e.part2[row * 9 + wid] = p0;
            sm.e.part2[(row + 32) * 9 + wid] = p1;
        }
    }
    __syncthreads();
    if (tid < 64) {
        float s = 0.0f;
#pragma unroll
        for (int w = 0; w < 8; w++) s += sm.e.part2[tid * 9 + w];
        sm.e.mul[tid] = s * (1.0f / 256.0f);
    }
    __syncthreads();
    // pass 2: variance
#pragma unroll
    for (int r = 0; r < 16; r++) {
        int row = (r & 3) + 8 * (r >> 2) + 4 * lh;
        float m0 = sm.e.mul[row], m1 = sm.e.mul[row + 32];
        float d0 = acc0[r] - m0, d1 = acc1[r] - m1;
        float p0 = d0 * d0, p1 = d1 * d1;
        p0 += __shfl_xor(p0, 1);  p0 += __shfl_xor(p0, 2);
        p0 += __shfl_xor(p0, 4);  p0 += __shfl_xor(p0, 8);
        p0 += __shfl_xor(p0, 16);
        p1 += __shfl_xor(p1, 1);  p1 += __shfl_xor(p1, 2);
        p1 += __shfl_xor(p1, 4);  p1 += __shfl_xor(p1, 8);
        p1 += __shfl_xor(p1, 16);
        if (lr == 0) {
            sm.e.part2[row * 9 + wid] = p0;
            sm.e.part2[(row + 32) * 9 + wid] = p1;
        }
    }
    __syncthreads();
    if (tid < 64) {
        float s = 0.0f;
#pragma unroll
        for (int w = 0; w < 8; w++) s += sm.e.part2[tid * 9 + w];
        sm.e.rsl[tid] = rsqrtf(s * (1.0f / 256.0f) + LN_EPS);
    }
    __syncthreads();
    // pass 3: LN affine + GELU + dot w2
#pragma unroll
    for (int r = 0; r < 16; r++) {
        int row = (r & 3) + 8 * (r >> 2) + 4 * lh;
        float m0 = sm.e.mul[row], m1 = sm.e.mul[row + 32];
        float rv0 = sm.e.rsl[row], rv1 = sm.e.rsl[row + 32];
        float v0 = (acc0[r] - m0) * rv0 * gc + bec;
        float v1 = (acc1[r] - m1) * rv1 * gc + bec;
        float p0 = gelu_exact(v0) * wc;
        float p1 = gelu_exact(v1) * wc;
        p0 += __shfl_xor(p0, 1);  p0 += __shfl_xor(p0, 2);
        p0 += __shfl_xor(p0, 4);  p0 += __shfl_xor(p0, 8);
        p0 += __shfl_xor(p0, 16);
        p1 += __shfl_xor(p1, 1);  p1 += __shfl_xor(p1, 2);
        p1 += __shfl_xor(p1, 4);  p1 += __shfl_xor(p1, 8);
        p1 += __shfl_xor(p1, 16);
        if (lr == 0) {
            sm.e.part2[row * 9 + wid] = p0;
            sm.e.part2[(row + 32) * 9 + wid] = p1;
        }
    }
    __syncthreads();
    if (tid < 64) {
        float s = 0.0f;
#pragma unroll
        for (int w = 0; w < 8; w++) s += sm.e.part2[tid * 9 + w];
        float logit = s + B2[0];
        float sc = 1.0f / (1.0f + expf(-logit));
        int t = tok0 + tid;
        sc *= (float)MASK[t];
        scf[t] = sc;
        out[O_SCORES + t] = sc;
    }
}

// ---------------- K2: span RLE + top-20 per row ----------------
__global__ __launch_bounds__(1024) void k_spans(
    const float* __restrict__ scf, int* __restrict__ spstart,
    int* __restrict__ splen, float* __restrict__ spavg, int* __restrict__ nsp,
    int* __restrict__ selstart, int* __restrict__ sellen,
    float* __restrict__ selavg, float* __restrict__ selvalid,
    float* __restrict__ out)
{
    const int r = blockIdx.x, tid = threadIdx.x;
    __shared__ float sc[S_LEN];
    __shared__ unsigned char ab[S_LEN];
    __shared__ int scn[1024];
    __shared__ float avgl[2048];
    __shared__ float rv[16];
    __shared__ int ri[16];

    float4 v = ((const float4*)(scf + (size_t)r * S_LEN))[tid];
    const int s0 = tid * 4;
    sc[s0 + 0] = v.x; sc[s0 + 1] = v.y; sc[s0 + 2] = v.z; sc[s0 + 3] = v.w;
    ab[s0 + 0] = (v.x >= THRESH);
    ab[s0 + 1] = (v.y >= THRESH);
    ab[s0 + 2] = (v.z >= THRESH);
    ab[s0 + 3] = (v.w >= THRESH);
    __syncthreads();

    bool st[4];
    int cnt = 0;
#pragma unroll
    for (int i = 0; i < 4; i++) {
        bool a = ab[s0 + i] != 0;
        bool p = (s0 + i == 0) ? false : (ab[s0 + i - 1] != 0);
        st[i] = a && !p;
        cnt += st[i] ? 1 : 0;
    }
    scn[tid] = cnt;
    __syncthreads();
    for (int off = 1; off < 1024; off <<= 1) {
        int mine = scn[tid];
        int add = (tid >= off) ? scn[tid - off] : 0;
        __syncthreads();
        scn[tid] = mine + add;
        __syncthreads();
    }
    const int total = scn[1023];
    int j = scn[tid] - cnt;
    for (int i = 0; i < 4; i++) {
        if (st[i]) {
            int s = s0 + i;
            float sum = 0.0f;
            int len = 0;
            int e = s;
            while (e < S_LEN && ab[e]) { sum += sc[e]; len++; e++; }
            float avg = sum / (float)len;
            spstart[r * 2048 + j] = s;
            splen[r * 2048 + j] = len;
            spavg[r * 2048 + j] = avg;
            avgl[j] = avg;
            j++;
        }
    }
    if (tid == 0) nsp[r] = total;
    __syncthreads();

    for (int k = 0; k < KMAX; k++) {
        float bv = -3.0e38f;
        int bi = 0x7FFFFFFF;
        for (int q = tid; q < total; q += 1024) {
            float a = avgl[q];
            if (a > bv) { bv = a; bi = q; }
        }
#pragma unroll
        for (int m = 1; m < 64; m <<= 1) {
            float ov = __shfl_xor(bv, m);
            int oi = __shfl_xor(bi, m);
            if (ov > bv || (ov == bv && oi < bi)) { bv = ov; bi = oi; }
        }
        if ((tid & 63) == 0) { rv[tid >> 6] = bv; ri[tid >> 6] = bi; }
        __syncthreads();
        if (tid < 64) {
            float v2 = (tid < 16) ? rv[tid] : -3.0e38f;
            int i2 = (tid < 16) ? ri[tid] : 0x7FFFFFFF;
#pragma unroll
            for (int m = 1; m < 16; m <<= 1) {
                float ov = __shfl_xor(v2, m);
                int oi = __shfl_xor(i2, m);
                if (ov > v2 || (ov == v2 && oi < i2)) { v2 = ov; i2 = oi; }
            }
            if (tid == 0) {
                int slot = r * KMAX + k;
                if (k < total) {
                    avgl[i2] = -3.0e38f;
                    int ln = splen[r * 2048 + i2];
                    float vd = (v2 >= THRESH && ln > 0) ? 1.0f : 0.0f;
                    selstart[slot] = spstart[r * 2048 + i2];
                    sellen[slot] = ln;
                    selavg[slot] = v2;
                    selvalid[slot] = vd;
                    out[O_ESC + slot] = v2 * vd;
                    out[O_VALIDK + slot] = vd;
                } else {
                    selstart[slot] = -1;
                    sellen[slot] = 0;
                    selavg[slot] = -1.0f;
                    selvalid[slot] = 0.0f;
                    out[O_ESC + slot] = 0.0f;
                    out[O_VALIDK + slot] = 0.0f;
                }
            }
        }
        __syncthreads();
    }
}

// ---------------- K3: fused tail, 1024 threads ----------------
__global__ __launch_bounds__(1024) void k_tail2(
    const float* __restrict__ X, const int* __restrict__ selstart,
    const int* __restrict__ sellen, const float* __restrict__ selvalid,
    const float* __restrict__ en_w1, const float* __restrict__ en_b1,
    const float* __restrict__ en_g, const float* __restrict__ en_be,
    const float* __restrict__ en_w2, const float* __restrict__ en_b2,
    const float* __restrict__ ty_w1, const float* __restrict__ ty_b1,
    const float* __restrict__ ty_g, const float* __restrict__ ty_be,
    const float* __restrict__ ty_w2, const float* __restrict__ ty_b2,
    float* __restrict__ out)
{
    const int slot = blockIdx.x, tid = threadIdx.x;
    __shared__ float xr[DMODEL];
    __shared__ float ps[DMODEL];
    __shared__ float g1[HDIM];
    __shared__ float red[8];
    __shared__ float lgp[4 * NTYPES];
    __shared__ float lg[NTYPES];

    const int r = slot / KMAX;
    const int s0 = selstart[slot], ln = sellen[slot];
    const float vd = selvalid[slot];
    const int j = tid & 255, p = tid >> 8;

    {
        float a = 0.0f;
        if (s0 >= 0) {
            const float* base = X + ((size_t)r * S_LEN + s0) * DMODEL + tid;
#pragma unroll 4
            for (int t = 0; t < ln; t++) a += base[(size_t)t * DMODEL];
        }
        const float dn = (ln > 0) ? (float)ln : 1.0f;
        xr[tid] = a / dn * vd;
    }
    __syncthreads();

    {
        float acc = 0.0f;
        const float* wp = en_w1 + (size_t)(p * 256) * HDIM + j;
        const float* xp = xr + p * 256;
#pragma unroll 16
        for (int k = 0; k < 256; k++) acc += xp[k] * wp[(size_t)k * HDIM];
        ps[tid] = acc;
    }
    __syncthreads();
    float h = 0.0f, mu = 0.0f;
    if (tid < 256) {
        h = ps[tid] + ps[256 + tid] + ps[512 + tid] + ps[768 + tid] + en_b1[tid];
        float s = h;
#pragma unroll
        for (int m = 1; m < 64; m <<= 1) s += __shfl_xor(s, m);
        if ((tid & 63) == 0) red[tid >> 6] = s;
    }
    __syncthreads();
    if (tid < 256) {
        mu = (red[0] + red[1] + red[2] + red[3]) * (1.0f / 256.0f);
        float d = h - mu;
        float s = d * d;
#pragma unroll
        for (int m = 1; m < 64; m <<= 1) s += __shfl_xor(s, m);
        if ((tid & 63) == 0) red[4 + (tid >> 6)] = s;
    }
    __syncthreads();
    if (tid < 256) {
        float var = (red[4] + red[5] + red[6] + red[7]) * (1.0f / 256.0f);
        float v = (h - mu) * rsqrtf(var + LN_EPS) * en_g[tid] + en_be[tid];
        g1[tid] = gelu_exact(v);
    }
    __syncthreads();

    {
        float acc = en_b2[tid];
        const float* wp = en_w2 + tid;
#pragma unroll 16
        for (int k = 0; k < 256; k++) acc += g1[k] * wp[(size_t)k * DMODEL];
        acc *= vd;
        out[O_ENH + (size_t)slot * DMODEL + tid] = acc;
        xr[tid] = acc;
    }
    __syncthreads();

    {
        float acc = 0.0f;
        const float* wp = ty_w1 + (size_t)(p * 256) * HDIM + j;
        const float* xp = xr + p * 256;
#pragma unroll 16
        for (int k = 0; k < 256; k++) acc += xp[k] * wp[(size_t)k * HDIM];
        ps[tid] = acc;
    }
    __syncthreads();
    h = 0.0f; mu = 0.0f;
    if (tid < 256) {
        h = ps[tid] + ps[256 + tid] + ps[512 + tid] + ps[768 + tid] + ty_b1[tid];
        float s = h;
#pragma unroll
        for (int m = 1; m < 64; m <<= 1) s += __shfl_xor(s, m);
        if ((tid & 63) == 0) red[tid >> 6] = s;
    }
    __syncthreads();
    if (tid < 256) {
        mu = (red[0] + red[1] + red[2] + red[3]) * (1.0f / 256.0f);
        float d = h - mu;
        float s = d * d;
#pragma unroll
        for (int m = 1; m < 64; m <<= 1) s += __shfl_xor(s, m);
        if ((tid & 63) == 0) red[4 + (tid >> 6)] = s;
    }
    __syncthreads();
    if (tid < 256) {
        float var = (red[4] + red[5] + red[6] + red[7]) * (1.0f / 256.0f);
        float v = (h - mu) * rsqrtf(var + LN_EPS) * ty_g[tid] + ty_be[tid];
        g1[tid] = gelu_exact(v);
    }
    __syncthreads();

    if (tid < 256) {
        float gv = g1[tid];
        float4 w0 = *(const float4*)&ty_w2[tid * NTYPES];
        float4 w1v = *(const float4*)&ty_w2[tid * NTYPES + 4];
        float pj[8] = {gv * w0.x, gv * w0.y, gv * w0.z, gv * w0.w,
                       gv * w1v.x, gv * w1v.y, gv * w1v.z, gv * w1v.w};
#pragma unroll
        for (int q = 0; q < 8; q++) {
            float s = pj[q];
#pragma unroll
            for (int m = 1; m < 64; m <<= 1) s += __shfl_xor(s, m);
            pj[q] = s;
        }
        if ((tid & 63) == 0) {
#pragma unroll
            for (int q = 0; q < 8; q++) lgp[(tid >> 6) * NTYPES + q] = pj[q];
        }
    }
    __syncthreads();
    if (tid < NTYPES) {
        float la = ty_b2[tid] + lgp[tid] + lgp[NTYPES + tid] +
                   lgp[2 * NTYPES + tid] + lgp[3 * NTYPES + tid];
        lg[tid] = la;
        out[O_TLOG + slot * NTYPES + tid] = la;
    }
    __syncthreads();
    if (tid == 0) {
        float mx = lg[0];
        int am = 0;
        for (int t = 1; t < NTYPES; t++)
            if (lg[t] > mx) { mx = lg[t]; am = t; }
        float ex[NTYPES], ssum = 0.0f;
        for (int t = 0; t < NTYPES; t++) { ex[t] = expf(lg[t] - mx); ssum += ex[t]; }
        for (int t = 0; t < NTYPES; t++)
            out[O_TPROB + slot * NTYPES + t] = ex[t] / ssum;
        out[O_TYPE + slot] = (float)am;
    }
}

extern "C" void kernel_launch(void* const* d_in, const int* in_sizes, int n_in,
                              void* d_out, int out_size, void* d_ws, size_t ws_size,
                              hipStream_t stream) {
    const float* X = (const float*)d_in[0];
    const int* MASK = (const int*)d_in[1];
    const float* sc_w1 = (const float*)d_in[2];
    const float* sc_b1 = (const float*)d_in[3];
    const float* sc_g  = (const float*)d_in[4];
    const float* sc_be = (const float*)d_in[5];
    const float* sc_w2 = (const float*)d_in[6];
    const float* sc_b2 = (const float*)d_in[7];
    const float* en_w1 = (const float*)d_in[8];
    const float* en_b1 = (const float*)d_in[9];
    const float* en_g  = (const float*)d_in[10];
    const float* en_be = (const float*)d_in[11];
    const float* en_w2 = (const float*)d_in[12];
    const float* en_b2 = (const float*)d_in[13];
    const float* ty_w1 = (const float*)d_in[14];
    const float* ty_b1 = (const float*)d_in[15];
    const float* ty_g  = (const float*)d_in[16];
    const float* ty_be = (const float*)d_in[17];
    const float* ty_w2 = (const float*)d_in[18];
    const float* ty_b2 = (const float*)d_in[19];

    float* out = (float*)d_out;
    float* wsf = (float*)d_ws;
    int* wsi = (int*)d_ws;
    _Float16* img = (_Float16*)(wsf + WS_IMG);

    k_prep<<<64, 256, 0, stream>>>(sc_w1, img);
    k_score8<<<(BATCH * S_LEN) / 64, 512, 0, stream>>>(
        X, img, sc_b1, sc_g, sc_be, sc_w2, sc_b2, MASK, wsf + WS_SCORES, out);
    k_spans<<<BATCH, 1024, 0, stream>>>(
        wsf + WS_SCORES, wsi + WS_SPSTART, wsi + WS_SPLEN, wsf + WS_SPAVG,
        wsi + WS_NSP, wsi + WS_SELSTART, wsi + WS_SELLEN, wsf + WS_SELAVG,
        wsf + WS_SELVALID, out);
    k_tail2<<<NSLOT, 1024, 0, stream>>>(
        X, wsi + WS_SELSTART, wsi + WS_SELLEN, wsf + WS_SELVALID,
        en_w1, en_b1, en_g, en_be, en_w2, en_b2,
        ty_w1, ty_b1, ty_g, ty_be, ty_w2, ty_b2, out);
}

// Round 12
// 150.182 us; speedup vs baseline: 1.1691x; 1.1691x over previous
//
#include <hip/hip_runtime.h>
#include <hip/hip_bf16.h>

#define S_LEN 4096
#define BATCH 8
#define DMODEL 1024
#define HDIM 256
#define NTYPES 8
#define KMAX 20
#define NSLOT (BATCH*KMAX)
#define THRESH 0.4f
#define LN_EPS 1e-5f
#define RSQRT2 0.70710678118654752f

// d_out offsets (f32 elements), reference return order
#define O_SCORES 0
#define O_ENH    32768
#define O_TLOG   196608
#define O_ESC    197888
#define O_TPROB  198048
#define O_TYPE   199328
#define O_VALIDK 199488

// ws layout (4-byte units)
#define WS_SCORES   0
#define WS_SPSTART  32768
#define WS_SPLEN    49152
#define WS_SPAVG    65536
#define WS_NSP      81920
#define WS_SELSTART 81936
#define WS_SELLEN   82096
#define WS_SELAVG   82256
#define WS_SELVALID 82416
// W1 hi/lo f16 image: 64 chunks x 8192 f16 (hi[4096] || lo[4096] per 16-k chunk)
#define WS_IMG      82576    // 262144 f32 = 1 MB

typedef _Float16 f16x2 __attribute__((ext_vector_type(2)));
typedef _Float16 f16x8 __attribute__((ext_vector_type(8)));
typedef float f32x16 __attribute__((ext_vector_type(16)));

#define APAD 40   // A row stride in f16: 80 B. slot = 5*row + lh, gcd(5,8)=1
                  // -> 32 lanes sweep all 8 LDS 16B-slot positions uniformly.

__device__ __forceinline__ float gelu_exact(float v) {
    return 0.5f * v * (1.0f + erff(v * RSQRT2));
}

// ---------------- K0: W1 -> chunked hi/lo f16 image (BK=16) --------
// chunk c (0..63): hi at [c*8192 + col*16 + k], lo at +4096
__global__ __launch_bounds__(256) void k_prep(
    const float* __restrict__ W1, _Float16* __restrict__ IMG)
{
    const int c = blockIdx.x;     // 16-k chunk
    const int n = threadIdx.x;    // col
    f16x8 hv[2], lv[2];
#pragma unroll
    for (int j = 0; j < 2; j++)
#pragma unroll
        for (int e = 0; e < 8; e++) {
            float w = W1[(size_t)(c * 16 + j * 8 + e) * HDIM + n];
            _Float16 h = (_Float16)w;
            hv[j][e] = h;
            lv[j][e] = (_Float16)(w - (float)h);
        }
    const int off = c * 8192 + n * 16;
    *(f16x8*)&IMG[off] = hv[0];
    *(f16x8*)&IMG[off + 8] = hv[1];
    *(f16x8*)&IMG[off + 4096] = lv[0];
    *(f16x8*)&IMG[off + 4096 + 8] = lv[1];
}

// ---------------- K1: scorer MLP — B from global, A in tiny LDS, FULL UNROLL --
// 512 blocks x 512 thr (8 waves); tile 64x256; BK=16; wave tile 32x64
__global__ __launch_bounds__(512, 4) void k_score9(
    const float* __restrict__ X, const _Float16* __restrict__ IMG,
    const float* __restrict__ B1, const float* __restrict__ G,
    const float* __restrict__ BE, const float* __restrict__ W2,
    const float* __restrict__ B2, const int* __restrict__ MASK,
    float* __restrict__ scf, float* __restrict__ out)
{
    union SM {
        _Float16 A[2][2][64 * APAD];   // [buf][hi/lo][row*APAD+k]  20 KB
        struct { float part2[64 * 5]; float mul[64]; float rsl[64]; } e;
    };
    __shared__ SM sm;

    const int tid = threadIdx.x;
    const int lane = tid & 63, wid = tid >> 6;
    const int lr = lane & 31, lh = lane >> 5;
    const int wm = (wid & 1) * 32;       // wave token offset {0,32}
    const int wn = (wid >> 1) * 64;      // wave col offset {0,64,128,192}
    const int wnid = wid >> 1;
    const int tok0 = blockIdx.x * 64;

    // X loader: thread covers 2 floats of one row per chunk
    const int xrow = tid >> 3, xk = (tid & 7) * 2;
    const float* xbase = X + (size_t)(tok0 + xrow) * DMODEL + xk;
    const int awoff = xrow * APAD + xk;           // A write f16 idx
    const int aroff = (wm + lr) * APAD + lh * 8;  // A read f16 idx (conflict-free)
    // B fragment f16 offsets within a chunk
    const int bo0 = (wn + lr) * 16 + lh * 8;
    const int bo1 = (wn + 32 + lr) * 16 + lh * 8;

    f32x16 acc0 = (f32x16)0.0f, acc1 = (f32x16)0.0f;

    // ---- prologue ----
    float2 x0 = *(const float2*)xbase;                 // X(0)
    f16x8 bh0c = *(const f16x8*)&IMG[bo0];             // B(0)
    f16x8 bh1c = *(const f16x8*)&IMG[bo1];
    f16x8 bl0c = *(const f16x8*)&IMG[4096 + bo0];
    f16x8 bl1c = *(const f16x8*)&IMG[4096 + bo1];
    {
        _Float16 h0 = (_Float16)x0.x, h1 = (_Float16)x0.y;
        f16x2 hh = {h0, h1};
        f16x2 ll = {(_Float16)(x0.x - (float)h0), (_Float16)(x0.y - (float)h1)};
        *(f16x2*)&sm.A[0][0][awoff] = hh;
        *(f16x2*)&sm.A[0][1][awoff] = ll;
    }
    float2 xnext = *(const float2*)(xbase + 16);       // X(1)
    f16x8 bh0n = *(const f16x8*)&IMG[8192 + bo0];      // B(1)
    f16x8 bh1n = *(const f16x8*)&IMG[8192 + bo1];
    f16x8 bl0n = *(const f16x8*)&IMG[8192 + 4096 + bo0];
    f16x8 bl1n = *(const f16x8*)&IMG[8192 + 4096 + bo1];
    asm volatile("s_waitcnt lgkmcnt(0)" ::: "memory");
    __builtin_amdgcn_s_barrier();
    __builtin_amdgcn_sched_barrier(0);

    int cur = 0;
#pragma unroll
    for (int c = 0; c < 64; ++c) {
        // issue 2-ahead loads (static offsets under full unroll)
        const int cf = (c + 2) & 63;
        float2 xfut = *(const float2*)(xbase + cf * 16);
        const _Float16* ib = IMG + cf * 8192;
        f16x8 fbh0 = *(const f16x8*)&ib[bo0];
        f16x8 fbh1 = *(const f16x8*)&ib[bo1];
        f16x8 fbl0 = *(const f16x8*)&ib[4096 + bo0];
        f16x8 fbl1 = *(const f16x8*)&ib[4096 + bo1];

        // A fragments from LDS (APAD=40: uniform slot spread, conflict-free)
        f16x8 fah = *(const f16x8*)&sm.A[cur][0][aroff];
        f16x8 fal = *(const f16x8*)&sm.A[cur][1][aroff];

        // 6 MFMA: 3-pass split x 2 col-frags
        acc0 = __builtin_amdgcn_mfma_f32_32x32x16_f16(fah, bh0c, acc0, 0, 0, 0);
        acc0 = __builtin_amdgcn_mfma_f32_32x32x16_f16(fal, bh0c, acc0, 0, 0, 0);
        acc0 = __builtin_amdgcn_mfma_f32_32x32x16_f16(fah, bl0c, acc0, 0, 0, 0);
        acc1 = __builtin_amdgcn_mfma_f32_32x32x16_f16(fah, bh1c, acc1, 0, 0, 0);
        acc1 = __builtin_amdgcn_mfma_f32_32x32x16_f16(fal, bh1c, acc1, 0, 0, 0);
        acc1 = __builtin_amdgcn_mfma_f32_32x32x16_f16(fah, bl1c, acc1, 0, 0, 0);

        // A handoff: convert X(c+1) (arrived; older than this iter's loads)
        {
            _Float16 h0 = (_Float16)xnext.x, h1 = (_Float16)xnext.y;
            f16x2 hh = {h0, h1};
            f16x2 ll = {(_Float16)(xnext.x - (float)h0), (_Float16)(xnext.y - (float)h1)};
            *(f16x2*)&sm.A[cur ^ 1][0][awoff] = hh;
            *(f16x2*)&sm.A[cur ^ 1][1][awoff] = ll;
        }
        asm volatile("s_waitcnt lgkmcnt(0)" ::: "memory");  // ds ops only; VMEM stays in flight
        __builtin_amdgcn_s_barrier();
        __builtin_amdgcn_sched_barrier(0);

        // rotate pipeline registers (pure renames under full unroll)
        bh0c = bh0n; bh1c = bh1n; bl0c = bl0n; bl1c = bl1n;
        bh0n = fbh0; bh1n = fbh1; bl0n = fbl0; bl1n = fbl1;
        xnext = xfut;
        cur ^= 1;
    }

    __syncthreads();   // A dead; union becomes epilogue arrays

    // ---- epilogue: bias, LN over 256 cols, GELU, dot w2, sigmoid, mask ----
    // C/D: col = wn + ni*32 + lr, row = wm + (r&3) + 8*(r>>2) + 4*lh
    float bcol[2], gcol[2], becol[2], wcol[2];
#pragma unroll
    for (int ni = 0; ni < 2; ni++) {
        int colg = wn + ni * 32 + lr;
        bcol[ni] = B1[colg];
        gcol[ni] = G[colg];
        becol[ni] = BE[colg];
        wcol[ni] = W2[colg];
    }
#pragma unroll
    for (int r = 0; r < 16; r++) { acc0[r] += bcol[0]; acc1[r] += bcol[1]; }

    // pass 1: mean
#pragma unroll
    for (int r = 0; r < 16; r++) {
        float p = acc0[r] + acc1[r];
        p += __shfl_xor(p, 1);  p += __shfl_xor(p, 2);
        p += __shfl_xor(p, 4);  p += __shfl_xor(p, 8);
        p += __shfl_xor(p, 16);
        int row = wm + (r & 3) + 8 * (r >> 2) + 4 * lh;
        if (lr == 0) sm.e.part2[row * 5 + wnid] = p;
    }
    __syncthreads();
    if (tid < 64)
        sm.e.mul[tid] = (sm.e.part2[tid * 5] + sm.e.part2[tid * 5 + 1] +
                         sm.e.part2[tid * 5 + 2] + sm.e.part2[tid * 5 + 3]) * (1.0f / 256.0f);
    __syncthreads();
    // pass 2: variance
#pragma unroll
    for (int r = 0; r < 16; r++) {
        int row = wm + (r & 3) + 8 * (r >> 2) + 4 * lh;
        float m = sm.e.mul[row];
        float d0 = acc0[r] - m, d1 = acc1[r] - m;
        float p = d0 * d0 + d1 * d1;
        p += __shfl_xor(p, 1);  p += __shfl_xor(p, 2);
        p += __shfl_xor(p, 4);  p += __shfl_xor(p, 8);
        p += __shfl_xor(p, 16);
        if (lr == 0) sm.e.part2[row * 5 + wnid] = p;
    }
    __syncthreads();
    if (tid < 64)
        sm.e.rsl[tid] = rsqrtf((sm.e.part2[tid * 5] + sm.e.part2[tid * 5 + 1] +
                                sm.e.part2[tid * 5 + 2] + sm.e.part2[tid * 5 + 3]) * (1.0f / 256.0f) + LN_EPS);
    __syncthreads();
    // pass 3: LN affine + GELU + dot w2
#pragma unroll
    for (int r = 0; r < 16; r++) {
        int row = wm + (r & 3) + 8 * (r >> 2) + 4 * lh;
        float m = sm.e.mul[row];
        float rv = sm.e.rsl[row];
        float v0 = (acc0[r] - m) * rv * gcol[0] + becol[0];
        float v1 = (acc1[r] - m) * rv * gcol[1] + becol[1];
        float p = gelu_exact(v0) * wcol[0] + gelu_exact(v1) * wcol[1];
        p += __shfl_xor(p, 1);  p += __shfl_xor(p, 2);
        p += __shfl_xor(p, 4);  p += __shfl_xor(p, 8);
        p += __shfl_xor(p, 16);
        if (lr == 0) sm.e.part2[row * 5 + wnid] = p;
    }
    __syncthreads();
    if (tid < 64) {
        float s = sm.e.part2[tid * 5] + sm.e.part2[tid * 5 + 1] +
                  sm.e.part2[tid * 5 + 2] + sm.e.part2[tid * 5 + 3];
        float logit = s + B2[0];
        float sc = 1.0f / (1.0f + expf(-logit));
        int t = tok0 + tid;
        sc *= (float)MASK[t];
        scf[t] = sc;
        out[O_SCORES + t] = sc;
    }
}

// ---------------- K2: span RLE + top-20 per row ----------------
__global__ __launch_bounds__(1024) void k_spans(
    const float* __restrict__ scf, int* __restrict__ spstart,
    int* __restrict__ splen, float* __restrict__ spavg, int* __restrict__ nsp,
    int* __restrict__ selstart, int* __restrict__ sellen,
    float* __restrict__ selavg, float* __restrict__ selvalid,
    float* __restrict__ out)
{
    const int r = blockIdx.x, tid = threadIdx.x;
    __shared__ float sc[S_LEN];
    __shared__ unsigned char ab[S_LEN];
    __shared__ int scn[1024];
    __shared__ float avgl[2048];
    __shared__ float rv[16];
    __shared__ int ri[16];

    float4 v = ((const float4*)(scf + (size_t)r * S_LEN))[tid];
    const int s0 = tid * 4;
    sc[s0 + 0] = v.x; sc[s0 + 1] = v.y; sc[s0 + 2] = v.z; sc[s0 + 3] = v.w;
    ab[s0 + 0] = (v.x >= THRESH);
    ab[s0 + 1] = (v.y >= THRESH);
    ab[s0 + 2] = (v.z >= THRESH);
    ab[s0 + 3] = (v.w >= THRESH);
    __syncthreads();

    bool st[4];
    int cnt = 0;
#pragma unroll
    for (int i = 0; i < 4; i++) {
        bool a = ab[s0 + i] != 0;
        bool p = (s0 + i == 0) ? false : (ab[s0 + i - 1] != 0);
        st[i] = a && !p;
        cnt += st[i] ? 1 : 0;
    }
    scn[tid] = cnt;
    __syncthreads();
    for (int off = 1; off < 1024; off <<= 1) {
        int mine = scn[tid];
        int add = (tid >= off) ? scn[tid - off] : 0;
        __syncthreads();
        scn[tid] = mine + add;
        __syncthreads();
    }
    const int total = scn[1023];
    int j = scn[tid] - cnt;
    for (int i = 0; i < 4; i++) {
        if (st[i]) {
            int s = s0 + i;
            float sum = 0.0f;
            int len = 0;
            int e = s;
            while (e < S_LEN && ab[e]) { sum += sc[e]; len++; e++; }
            float avg = sum / (float)len;
            spstart[r * 2048 + j] = s;
            splen[r * 2048 + j] = len;
            spavg[r * 2048 + j] = avg;
            avgl[j] = avg;
            j++;
        }
    }
    if (tid == 0) nsp[r] = total;
    __syncthreads();

    for (int k = 0; k < KMAX; k++) {
        float bv = -3.0e38f;
        int bi = 0x7FFFFFFF;
        for (int q = tid; q < total; q += 1024) {
            float a = avgl[q];
            if (a > bv) { bv = a; bi = q; }
        }
#pragma unroll
        for (int m = 1; m < 64; m <<= 1) {
            float ov = __shfl_xor(bv, m);
            int oi = __shfl_xor(bi, m);
            if (ov > bv || (ov == bv && oi < bi)) { bv = ov; bi = oi; }
        }
        if ((tid & 63) == 0) { rv[tid >> 6] = bv; ri[tid >> 6] = bi; }
        __syncthreads();
        if (tid < 64) {
            float v2 = (tid < 16) ? rv[tid] : -3.0e38f;
            int i2 = (tid < 16) ? ri[tid] : 0x7FFFFFFF;
#pragma unroll
            for (int m = 1; m < 16; m <<= 1) {
                float ov = __shfl_xor(v2, m);
                int oi = __shfl_xor(i2, m);
                if (ov > v2 || (ov == v2 && oi < i2)) { v2 = ov; i2 = oi; }
            }
            if (tid == 0) {
                int slot = r * KMAX + k;
                if (k < total) {
                    avgl[i2] = -3.0e38f;
                    int ln = splen[r * 2048 + i2];
                    float vd = (v2 >= THRESH && ln > 0) ? 1.0f : 0.0f;
                    selstart[slot] = spstart[r * 2048 + i2];
                    sellen[slot] = ln;
                    selavg[slot] = v2;
                    selvalid[slot] = vd;
                    out[O_ESC + slot] = v2 * vd;
                    out[O_VALIDK + slot] = vd;
                } else {
                    selstart[slot] = -1;
                    sellen[slot] = 0;
                    selavg[slot] = -1.0f;
                    selvalid[slot] = 0.0f;
                    out[O_ESC + slot] = 0.0f;
                    out[O_VALIDK + slot] = 0.0f;
                }
            }
        }
        __syncthreads();
    }
}

// ---------------- K3: fused tail, 1024 threads ----------------
__global__ __launch_bounds__(1024) void k_tail2(
    const float* __restrict__ X, const int* __restrict__ selstart,
    const int* __restrict__ sellen, const float* __restrict__ selvalid,
    const float* __restrict__ en_w1, const float* __restrict__ en_b1,
    const float* __restrict__ en_g, const float* __restrict__ en_be,
    const float* __restrict__ en_w2, const float* __restrict__ en_b2,
    const float* __restrict__ ty_w1, const float* __restrict__ ty_b1,
    const float* __restrict__ ty_g, const float* __restrict__ ty_be,
    const float* __restrict__ ty_w2, const float* __restrict__ ty_b2,
    float* __restrict__ out)
{
    const int slot = blockIdx.x, tid = threadIdx.x;
    __shared__ float xr[DMODEL];
    __shared__ float ps[DMODEL];
    __shared__ float g1[HDIM];
    __shared__ float red[8];
    __shared__ float lgp[4 * NTYPES];
    __shared__ float lg[NTYPES];

    const int r = slot / KMAX;
    const int s0 = selstart[slot], ln = sellen[slot];
    const float vd = selvalid[slot];
    const int j = tid & 255, p = tid >> 8;

    {
        float a = 0.0f;
        if (s0 >= 0) {
            const float* base = X + ((size_t)r * S_LEN + s0) * DMODEL + tid;
#pragma unroll 4
            for (int t = 0; t < ln; t++) a += base[(size_t)t * DMODEL];
        }
        const float dn = (ln > 0) ? (float)ln : 1.0f;
        xr[tid] = a / dn * vd;
    }
    __syncthreads();

    {
        float acc = 0.0f;
        const float* wp = en_w1 + (size_t)(p * 256) * HDIM + j;
        const float* xp = xr + p * 256;
#pragma unroll 16
        for (int k = 0; k < 256; k++) acc += xp[k] * wp[(size_t)k * HDIM];
        ps[tid] = acc;
    }
    __syncthreads();
    float h = 0.0f, mu = 0.0f;
    if (tid < 256) {
        h = ps[tid] + ps[256 + tid] + ps[512 + tid] + ps[768 + tid] + en_b1[tid];
        float s = h;
#pragma unroll
        for (int m = 1; m < 64; m <<= 1) s += __shfl_xor(s, m);
        if ((tid & 63) == 0) red[tid >> 6] = s;
    }
    __syncthreads();
    if (tid < 256) {
        mu = (red[0] + red[1] + red[2] + red[3]) * (1.0f / 256.0f);
        float d = h - mu;
        float s = d * d;
#pragma unroll
        for (int m = 1; m < 64; m <<= 1) s += __shfl_xor(s, m);
        if ((tid & 63) == 0) red[4 + (tid >> 6)] = s;
    }
    __syncthreads();
    if (tid < 256) {
        float var = (red[4] + red[5] + red[6] + red[7]) * (1.0f / 256.0f);
        float v = (h - mu) * rsqrtf(var + LN_EPS) * en_g[tid] + en_be[tid];
        g1[tid] = gelu_exact(v);
    }
    __syncthreads();

    {
        float acc = en_b2[tid];
        const float* wp = en_w2 + tid;
#pragma unroll 16
        for (int k = 0; k < 256; k++) acc += g1[k] * wp[(size_t)k * DMODEL];
        acc *= vd;
        out[O_ENH + (size_t)slot * DMODEL + tid] = acc;
        xr[tid] = acc;
    }
    __syncthreads();

    {
        float acc = 0.0f;
        const float* wp = ty_w1 + (size_t)(p * 256) * HDIM + j;
        const float* xp = xr + p * 256;
#pragma unroll 16
        for (int k = 0; k < 256; k++) acc += xp[k] * wp[(size_t)k * HDIM];
        ps[tid] = acc;
    }
    __syncthreads();
    h = 0.0f; mu = 0.0f;
    if (tid < 256) {
        h = ps[tid] + ps[256 + tid] + ps[512 + tid] + ps[768 + tid] + ty_b1[tid];
        float s = h;
#pragma unroll
        for (int m = 1; m < 64; m <<= 1) s += __shfl_xor(s, m);
        if ((tid & 63) == 0) red[tid >> 6] = s;
    }
    __syncthreads();
    if (tid < 256) {
        mu = (red[0] + red[1] + red[2] + red[3]) * (1.0f / 256.0f);
        float d = h - mu;
        float s = d * d;
#pragma unroll
        for (int m = 1; m < 64; m <<= 1) s += __shfl_xor(s, m);
        if ((tid & 63) == 0) red[4 + (tid >> 6)] = s;
    }
    __syncthreads();
    if (tid < 256) {
        float var = (red[4] + red[5] + red[6] + red[7]) * (1.0f / 256.0f);
        float v = (h - mu) * rsqrtf(var + LN_EPS) * ty_g[tid] + ty_be[tid];
        g1[tid] = gelu_exact(v);
    }
    __syncthreads();

    if (tid < 256) {
        float gv = g1[tid];
        float4 w0 = *(const float4*)&ty_w2[tid * NTYPES];
        float4 w1v = *(const float4*)&ty_w2[tid * NTYPES + 4];
        float pj[8] = {gv * w0.x, gv * w0.y, gv * w0.z, gv * w0.w,
                       gv * w1v.x, gv * w1v.y, gv * w1v.z, gv * w1v.w};
#pragma unroll
        for (int q = 0; q < 8; q++) {
            float s = pj[q];
#pragma unroll
            for (int m = 1; m < 64; m <<= 1) s += __shfl_xor(s, m);
            pj[q] = s;
        }
        if ((tid & 63) == 0) {
#pragma unroll
            for (int q = 0; q < 8; q++) lgp[(tid >> 6) * NTYPES + q] = pj[q];
        }
    }
    __syncthreads();
    if (tid < NTYPES) {
        float la = ty_b2[tid] + lgp[tid] + lgp[NTYPES + tid] +
                   lgp[2 * NTYPES + tid] + lgp[3 * NTYPES + tid];
        lg[tid] = la;
        out[O_TLOG + slot * NTYPES + tid] = la;
    }
    __syncthreads();
    if (tid == 0) {
        float mx = lg[0];
        int am = 0;
        for (int t = 1; t < NTYPES; t++)
            if (lg[t] > mx) { mx = lg[t]; am = t; }
        float ex[NTYPES], ssum = 0.0f;
        for (int t = 0; t < NTYPES; t++) { ex[t] = expf(lg[t] - mx); ssum += ex[t]; }
        for (int t = 0; t < NTYPES; t++)
            out[O_TPROB + slot * NTYPES + t] = ex[t] / ssum;
        out[O_TYPE + slot] = (float)am;
    }
}

extern "C" void kernel_launch(void* const* d_in, const int* in_sizes, int n_in,
                              void* d_out, int out_size, void* d_ws, size_t ws_size,
                              hipStream_t stream) {
    const float* X = (const float*)d_in[0];
    const int* MASK = (const int*)d_in[1];
    const float* sc_w1 = (const float*)d_in[2];
    const float* sc_b1 = (const float*)d_in[3];
    const float* sc_g  = (const float*)d_in[4];
    const float* sc_be = (const float*)d_in[5];
    const float* sc_w2 = (const float*)d_in[6];
    const float* sc_b2 = (const float*)d_in[7];
    const float* en_w1 = (const float*)d_in[8];
    const float* en_b1 = (const float*)d_in[9];
    const float* en_g  = (const float*)d_in[10];
    const float* en_be = (const float*)d_in[11];
    const float* en_w2 = (const float*)d_in[12];
    const float* en_b2 = (const float*)d_in[13];
    const float* ty_w1 = (const float*)d_in[14];
    const float* ty_b1 = (const float*)d_in[15];
    const float* ty_g  = (const float*)d_in[16];
    const float* ty_be = (const float*)d_in[17];
    const float* ty_w2 = (const float*)d_in[18];
    const float* ty_b2 = (const float*)d_in[19];

    float* out = (float*)d_out;
    float* wsf = (float*)d_ws;
    int* wsi = (int*)d_ws;
    _Float16* img = (_Float16*)(wsf + WS_IMG);

    k_prep<<<64, 256, 0, stream>>>(sc_w1, img);
    k_score9<<<(BATCH * S_LEN) / 64, 512, 0, stream>>>(
        X, img, sc_b1, sc_g, sc_be, sc_w2, sc_b2, MASK, wsf + WS_SCORES, out);
    k_spans<<<BATCH, 1024, 0, stream>>>(
        wsf + WS_SCORES, wsi + WS_SPSTART, wsi + WS_SPLEN, wsf + WS_SPAVG,
        wsi + WS_NSP, wsi + WS_SELSTART, wsi + WS_SELLEN, wsf + WS_SELAVG,
        wsf + WS_SELVALID, out);
    k_tail2<<<NSLOT, 1024, 0, stream>>>(
        X, wsi + WS_SELSTART, wsi + WS_SELLEN, wsf + WS_SELVALID,
        en_w1, en_b1, en_g, en_be, en_w2, en_b2,
        ty_w1, ty_b1, ty_g, ty_be, ty_w2, ty_b2, out);
}